// Round 1
// baseline (861.256 us; speedup 1.0000x reference)
//
#include <hip/hip_runtime.h>
#include <hip/hip_bf16.h>
#include <stdint.h>

#define B_SZ  16
#define S_SZ  2048
#define D_SZ  1024
#define FF_SZ 4096
#define DT_SZ 512

typedef __bf16 bf16x8 __attribute__((ext_vector_type(8)));
typedef float  f32x4  __attribute__((ext_vector_type(4)));
typedef short  short8 __attribute__((ext_vector_type(8)));

__device__ __forceinline__ short f2bf(float x) {
    union { float f; uint32_t u; } v; v.f = x;
    uint32_t r = (v.u + 0x7fffu + ((v.u >> 16) & 1u)) >> 16;  // RNE
    return (short)(uint16_t)r;
}

// ---------------- cast f32 -> bf16, 8 elems/thread ----------------
__global__ void cast_x_kernel(const float* __restrict__ src, short* __restrict__ dst, int n8) {
    int i = blockIdx.x * 256 + threadIdx.x;
    if (i >= n8) return;
    const float4* s4 = reinterpret_cast<const float4*>(src);
    float4 a = s4[2 * i], b = s4[2 * i + 1];
    short8 v;
    v[0] = f2bf(a.x); v[1] = f2bf(a.y); v[2] = f2bf(a.z); v[3] = f2bf(a.w);
    v[4] = f2bf(b.x); v[5] = f2bf(b.y); v[6] = f2bf(b.z); v[7] = f2bf(b.w);
    reinterpret_cast<short8*>(dst)[i] = v;
}

// ---------------- transpose + cast: src f32 [R][C] -> dst bf16 [C][R] ----------------
__global__ void transpose_cast_kernel(const float* __restrict__ src, short* __restrict__ dst,
                                      int R, int C) {
    __shared__ float tile[32][33];
    int c0 = blockIdx.x * 32, r0 = blockIdx.y * 32;
    int tx = threadIdx.x, ty = threadIdx.y;   // 32 x 8
#pragma unroll
    for (int i = 0; i < 32; i += 8)
        tile[ty + i][tx] = src[(size_t)(r0 + ty + i) * C + (c0 + tx)];
    __syncthreads();
#pragma unroll
    for (int i = 0; i < 32; i += 8)
        dst[(size_t)(c0 + ty + i) * R + (r0 + tx)] = f2bf(tile[tx][ty + i]);
}

// ---------------- bf16 GEMM: C = A(MxK) * Bt(NxK)^T ----------------
// 128x128 tile, BK=32, 256 threads = 4 waves (2x2), each wave 64x64 via 4x4 MFMA frags.
template <bool GELU_BF16>
__global__ void gemm_bt_kernel(const short* __restrict__ A, const short* __restrict__ Bt,
                               void* __restrict__ Cout, int M, int N, int K) {
    __shared__ short Als[128 * 32];   // [m][k]
    __shared__ short Bls[128 * 32];   // [n][k]
    const int t  = threadIdx.x;
    const int w  = t >> 6;
    const int l  = t & 63;
    const int wm = w >> 1, wn = w & 1;
    const int m0 = blockIdx.x * 128;
    const int n0 = blockIdx.y * 128;
    const int lrow  = l >> 2;          // 0..15 (staging row within wave's 16-row slab)
    const int lcol8 = (l & 3) << 3;    // 0,8,16,24 (staging k offset)
    const int kq  = l >> 4;            // 0..3 (fragment k-quarter / D-row group)
    const int l15 = l & 15;

    f32x4 acc[4][4];
#pragma unroll
    for (int mi = 0; mi < 4; ++mi)
#pragma unroll
        for (int ni = 0; ni < 4; ++ni)
            acc[mi][ni] = (f32x4){0.f, 0.f, 0.f, 0.f};

    for (int k0 = 0; k0 < K; k0 += 32) {
        __syncthreads();   // WAR: previous iter's ds_reads done before overwrite
#pragma unroll
        for (int i = 0; i < 2; ++i) {
            const int row = i * 64 + w * 16 + lrow;
            const short* ga = A + (size_t)(m0 + row) * K + (k0 + lcol8);
            __builtin_amdgcn_global_load_lds(
                (__attribute__((address_space(1))) void*)ga,
                (__attribute__((address_space(3))) void*)&Als[(i * 64 + w * 16) * 32],
                16, 0, 0);
            const short* gb = Bt + (size_t)(n0 + row) * K + (k0 + lcol8);
            __builtin_amdgcn_global_load_lds(
                (__attribute__((address_space(1))) void*)gb,
                (__attribute__((address_space(3))) void*)&Bls[(i * 64 + w * 16) * 32],
                16, 0, 0);
        }
        __syncthreads();   // drains vmcnt before LDS reads

        bf16x8 af[4], bfr[4];
#pragma unroll
        for (int mi = 0; mi < 4; ++mi)
            af[mi] = *reinterpret_cast<const bf16x8*>(&Als[(wm * 64 + mi * 16 + l15) * 32 + kq * 8]);
#pragma unroll
        for (int ni = 0; ni < 4; ++ni)
            bfr[ni] = *reinterpret_cast<const bf16x8*>(&Bls[(wn * 64 + ni * 16 + l15) * 32 + kq * 8]);
#pragma unroll
        for (int mi = 0; mi < 4; ++mi)
#pragma unroll
            for (int ni = 0; ni < 4; ++ni)
                acc[mi][ni] = __builtin_amdgcn_mfma_f32_16x16x32_bf16(af[mi], bfr[ni],
                                                                      acc[mi][ni], 0, 0, 0);
    }

    // D layout (m89-verified): col = lane&15, row = (lane>>4)*4 + reg
    const int row_base = m0 + wm * 64 + kq * 4;
    const int col_base = n0 + wn * 64 + l15;
    if constexpr (GELU_BF16) {
        short* C = reinterpret_cast<short*>(Cout);
#pragma unroll
        for (int mi = 0; mi < 4; ++mi)
#pragma unroll
            for (int r = 0; r < 4; ++r) {
                const size_t ro = (size_t)(row_base + mi * 16 + r) * N;
#pragma unroll
                for (int ni = 0; ni < 4; ++ni) {
                    float x = acc[mi][ni][r];
                    // jax.nn.gelu(approximate=True): 0.5*x*(1+tanh(0.79788456*(x+0.044715*x^3)))
                    float u = 0.7978845608028654f * (x + 0.044715f * x * x * x);
                    float g = x / (1.f + __expf(-2.f * u));
                    C[ro + col_base + ni * 16] = f2bf(g);
                }
            }
    } else {
        float* C = reinterpret_cast<float*>(Cout);
#pragma unroll
        for (int mi = 0; mi < 4; ++mi)
#pragma unroll
            for (int r = 0; r < 4; ++r) {
                const size_t ro = (size_t)(row_base + mi * 16 + r) * N;
#pragma unroll
                for (int ni = 0; ni < 4; ++ni)
                    C[ro + col_base + ni * 16] = acc[mi][ni][r];
            }
    }
}

// ---------------- intervention: out[b, eot[b], 0:512] = row[0:512] @ Wrot @ Winv ----------------
__global__ void intervention_kernel(const float* __restrict__ Wrot, const float* __restrict__ Winv,
                                    const int* __restrict__ eot, float* __restrict__ out) {
    __shared__ float tgt[DT_SZ];
    __shared__ float tmp[DT_SZ];
    const int b = blockIdx.x;
    const int j = threadIdx.x;
    float* row = out + ((size_t)b * S_SZ + eot[b]) * D_SZ;
    tgt[j] = row[j];                      // ST=0 slice
    __syncthreads();
    float s = 0.f;
#pragma unroll 8
    for (int i = 0; i < DT_SZ; ++i) s = fmaf(tgt[i], Wrot[(size_t)i * DT_SZ + j], s);
    tmp[j] = s;
    __syncthreads();
    float s2 = 0.f;
#pragma unroll 8
    for (int i = 0; i < DT_SZ; ++i) s2 = fmaf(tmp[i], Winv[(size_t)i * DT_SZ + j], s2);
    row[j] = s2;
}

extern "C" void kernel_launch(void* const* d_in, const int* in_sizes, int n_in,
                              void* d_out, int out_size, void* d_ws, size_t ws_size,
                              hipStream_t stream) {
    const float* hidden = (const float*)d_in[0];
    const float* W1     = (const float*)d_in[1];
    const float* W2     = (const float*)d_in[2];
    const float* Wrot   = (const float*)d_in[3];
    const float* Winv   = (const float*)d_in[4];
    const int*   eot    = (const int*)d_in[5];
    float* out = (float*)d_out;

    const int M  = B_SZ * S_SZ;   // 32768
    const int K1 = D_SZ, N1 = FF_SZ;
    const int K2 = FF_SZ, N2 = D_SZ;

    // ws layout: W1t (FF x D bf16) | W2t (D x FF bf16) | Xbf chunk (Mc x D bf16) | C1 chunk (Mc x FF bf16)
    short* W1t = (short*)d_ws;
    short* W2t = W1t + (size_t)FF_SZ * D_SZ;
    short* Xbf = W2t + (size_t)FF_SZ * D_SZ;
    const size_t fixed_bytes = 2ull * (size_t)FF_SZ * D_SZ * sizeof(short);  // 16 MiB
    const size_t per_row = (size_t)D_SZ * 2 + (size_t)FF_SZ * 2;             // 10240 B
    size_t rem = ws_size > fixed_bytes ? ws_size - fixed_bytes : 0;
    int Mc = (int)(rem / per_row);
    Mc = (Mc / 128) * 128;
    if (Mc < 128) Mc = 128;
    if (Mc > M) Mc = M;
    short* C1 = Xbf + (size_t)Mc * D_SZ;

    transpose_cast_kernel<<<dim3(FF_SZ / 32, D_SZ / 32), dim3(32, 8), 0, stream>>>(W1, W1t, D_SZ, FF_SZ);
    transpose_cast_kernel<<<dim3(D_SZ / 32, FF_SZ / 32), dim3(32, 8), 0, stream>>>(W2, W2t, FF_SZ, D_SZ);

    for (int ms = 0; ms < M; ms += Mc) {
        const int mc = (M - ms < Mc) ? (M - ms) : Mc;   // multiple of 128
        const int n8 = mc * D_SZ / 8;
        cast_x_kernel<<<(n8 + 255) / 256, 256, 0, stream>>>(hidden + (size_t)ms * D_SZ, Xbf, n8);
        gemm_bt_kernel<true ><<<dim3(mc / 128, N1 / 128), 256, 0, stream>>>(Xbf, W1t, C1, mc, N1, K1);
        gemm_bt_kernel<false><<<dim3(mc / 128, N2 / 128), 256, 0, stream>>>(C1, W2t,
                                                                            out + (size_t)ms * D_SZ,
                                                                            mc, N2, K2);
    }
    intervention_kernel<<<B_SZ, DT_SZ, 0, stream>>>(Wrot, Winv, eot, out);
}